// Round 10
// baseline (197.859 us; speedup 1.0000x reference)
//
#include <hip/hip_runtime.h>

#define BATCH 4096
#define T 256
#define IN 64
#define CELL 128
#define ZDIM 256
#define OUTD 64
#define M 16   // batch rows per block (one MFMA row-tile)

using f32x4 = __attribute__((ext_vector_type(4))) float;
using f4    = __attribute__((ext_vector_type(4))) float;
using h16x8 = __attribute__((ext_vector_type(8))) _Float16;
using fp16x2 = __attribute__((ext_vector_type(2))) __fp16;   // cvt_pkrtz result type
typedef unsigned int u32t;

union h8cast { h16x8 v; fp16x2 h[4]; };
union pkcast { fp16x2 h; u32t u; };

#define MFMA16(A, B, C) __builtin_amdgcn_mfma_f32_16x16x32_f16(A, B, C, 0, 0, 0)

// gate for cell pair (colA=32w+2q, colB=colA+1) at row 4g+I.
// Weights/biases pre-scaled: f-cols by -log2e, g-cols by 2*log2e, so
// sigmoid(zf) = rcp(1+exp2(zf')) and tanh(zg) = 1-2*rcp(exp2(zg')+1).
#define GATEPK(I)                                                               \
  {                                                                             \
    float fgA = __builtin_amdgcn_rcpf(1.f + __builtin_amdgcn_exp2f(fa[I]));     \
    float thA = 1.f - 2.f * __builtin_amdgcn_rcpf(__builtin_amdgcn_exp2f(ga[I]) + 1.f); \
    float cnA = fgA * (cregA[I] - thA) + thA;                                   \
    float fgB = __builtin_amdgcn_rcpf(1.f + __builtin_amdgcn_exp2f(fb[I]));     \
    float thB = 1.f - 2.f * __builtin_amdgcn_rcpf(__builtin_amdgcn_exp2f(gb[I]) + 1.f); \
    float cnB = fgB * (cregB[I] - thB) + thB;                                   \
    cregA[I] = cnA; cregB[I] = cnB;                                             \
    pkcast pk_; pk_.h = __builtin_amdgcn_cvt_pkrtz(cnA, cnB);                   \
    *(u32t*)(cn_ + woPk[I]) = pk_.u;                                            \
  }

// One recurrence step. Reads c(fp16) from cbuf[P], writes c'(fp16) to cbuf[P^1].
// XC* hold x(TT) raw fp32 (loaded 2 steps ago); refilled with x((TT+2)&255).
#define STEP(XC0, XC1, XC2, XC3, TT, P)                                         \
  {                                                                             \
    const char* cb_ = cbuf[P];                                                  \
    h16x8 ca0 = *(const h16x8*)(cb_ + ro[0]);                                   \
    h16x8 ca1 = *(const h16x8*)(cb_ + ro[1]);                                   \
    h16x8 ca2 = *(const h16x8*)(cb_ + ro[2]);                                   \
    h16x8 ca3 = *(const h16x8*)(cb_ + ro[3]);                                   \
    h8cast ux0, ux1;                                                            \
    ux0.h[0] = __builtin_amdgcn_cvt_pkrtz(XC0[0], XC0[1]);                      \
    ux0.h[1] = __builtin_amdgcn_cvt_pkrtz(XC0[2], XC0[3]);                      \
    ux0.h[2] = __builtin_amdgcn_cvt_pkrtz(XC1[0], XC1[1]);                      \
    ux0.h[3] = __builtin_amdgcn_cvt_pkrtz(XC1[2], XC1[3]);                      \
    ux1.h[0] = __builtin_amdgcn_cvt_pkrtz(XC2[0], XC2[1]);                      \
    ux1.h[1] = __builtin_amdgcn_cvt_pkrtz(XC2[2], XC2[3]);                      \
    ux1.h[2] = __builtin_amdgcn_cvt_pkrtz(XC3[0], XC3[1]);                      \
    ux1.h[3] = __builtin_amdgcn_cvt_pkrtz(XC3[2], XC3[3]);                      \
    const h16x8 xa0 = ux0.v, xa1 = ux1.v;                                       \
    /* refill: uniform step offset, per-lane base */                            \
    {                                                                           \
      const int tn = ((TT) + 2) & (T - 1);                                      \
      const float* xp = xbase + (size_t)tn * IN;                                \
      XC0 = *(const f4*)(xp);                                                   \
      XC1 = *(const f4*)(xp + 4);                                               \
      XC2 = *(const f4*)(xp + 32);                                              \
      XC3 = *(const f4*)(xp + 36);                                              \
    }                                                                           \
    /* 4 accumulator chains, depth 6; C-in seeded with scaled bias */           \
    f32x4 fa = MFMA16(xa0, bA0, bqA);                                           \
    f32x4 fb = MFMA16(xa0, bB0, bqB);                                           \
    f32x4 ga = MFMA16(xa0, bC0, bqC);                                           \
    f32x4 gb = MFMA16(xa0, bD0, bqD);                                           \
    fa = MFMA16(xa1, bA1, fa); fb = MFMA16(xa1, bB1, fb);                       \
    ga = MFMA16(xa1, bC1, ga); gb = MFMA16(xa1, bD1, gb);                       \
    fa = MFMA16(ca0, bA2, fa); fb = MFMA16(ca0, bB2, fb);                       \
    ga = MFMA16(ca0, bC2, ga); gb = MFMA16(ca0, bD2, gb);                       \
    fa = MFMA16(ca1, bA3, fa); fb = MFMA16(ca1, bB3, fb);                       \
    ga = MFMA16(ca1, bC3, ga); gb = MFMA16(ca1, bD3, gb);                       \
    fa = MFMA16(ca2, bA4, fa); fb = MFMA16(ca2, bB4, fb);                       \
    ga = MFMA16(ca2, bC4, ga); gb = MFMA16(ca2, bD4, gb);                       \
    fa = MFMA16(ca3, bA5, fa); fb = MFMA16(ca3, bB5, fb);                       \
    ga = MFMA16(ca3, bC5, ga); gb = MFMA16(ca3, bD5, gb);                       \
    char* cn_ = cbuf[(P) ^ 1];                                                  \
    GATEPK(0) GATEPK(1) GATEPK(2) GATEPK(3)                                     \
    /* LDS-only barrier: ds_writes visible, global prefetch stays in flight */  \
    asm volatile("s_waitcnt lgkmcnt(0)\n\ts_barrier" ::: "memory");             \
  }

__global__ __launch_bounds__(256, 1)
void llrnn_f16(const float* __restrict__ in,   // [B,T,IN]
               const float* __restrict__ Km,   // [IN,ZDIM]
               const float* __restrict__ Rm,   // [CELL,ZDIM]
               const float* __restrict__ bz,   // [ZDIM]
               const float* __restrict__ Wd,   // [CELL,OUTD]
               const float* __restrict__ bd,   // [OUTD]
               float* __restrict__ out)        // [B,OUTD]
{
  // c state as fp16 [16 rows][128 cells], chunk-XOR-swizzled, double-buffered.
  // byte(r,j) = r*256 + 16*((j>>3)^(r&7)) + (2j&15)
  __shared__ __align__(16) char cbuf[2][M * CELL * 2];   // 2 x 4 KB
  __shared__ float cfin[M * CELL];

  const int tid = threadIdx.x;
  const int w = tid >> 6;        // wave 0..3
  const int l = tid & 63;
  const int q = l & 15;          // A-row / D-col within tile
  const int g = l >> 4;          // k-group 0..3
  const int rb = blockIdx.x * M;
  const int colA = 32 * w + 2 * q;    // even cell column owned by this lane
  const int colB = colA + 1;          // odd cell column (adjacent -> packed write)

  // zero c(t=0) buffer (4 KB, 256 threads x 4 u32)
  {
    u32t* z0 = (u32t*)cbuf[0];
    z0[tid] = 0; z0[tid + 256] = 0; z0[tid + 512] = 0; z0[tid + 768] = 0;
  }

  const float SF = -1.44269504f;  // -log2(e): fold into f-gate weights
  const float SG =  2.88539008f;  //  2*log2(e): fold into g-gate weights

  // ---- preload scaled weight columns as fp16 frags (A=f even, B=f odd,
  //      C=g even, D=g odd), pinned in arch VGPRs ----
  h16x8 bA0,bA1,bA2,bA3,bA4,bA5, bB0,bB1,bB2,bB3,bB4,bB5,
        bC0,bC1,bC2,bC3,bC4,bC5, bD0,bD1,bD2,bD3,bD4,bD5;
#define LOADW(DST, COL, KT, SC)                                                 \
  {                                                                             \
    _Pragma("unroll") for (int e = 0; e < 8; ++e) {                             \
      const int krow = 32 * (KT) + 8 * g + e;                                   \
      const float* src = ((KT) < 2) ? (Km + (size_t)krow * ZDIM)                \
                                    : (Rm + (size_t)(krow - IN) * ZDIM);        \
      DST[e] = (_Float16)(src[COL] * (SC));                                     \
    }                                                                           \
  }
  LOADW(bA0,colA,0,SF) LOADW(bA1,colA,1,SF) LOADW(bA2,colA,2,SF)
  LOADW(bA3,colA,3,SF) LOADW(bA4,colA,4,SF) LOADW(bA5,colA,5,SF)
  LOADW(bB0,colB,0,SF) LOADW(bB1,colB,1,SF) LOADW(bB2,colB,2,SF)
  LOADW(bB3,colB,3,SF) LOADW(bB4,colB,4,SF) LOADW(bB5,colB,5,SF)
  LOADW(bC0,colA+CELL,0,SG) LOADW(bC1,colA+CELL,1,SG) LOADW(bC2,colA+CELL,2,SG)
  LOADW(bC3,colA+CELL,3,SG) LOADW(bC4,colA+CELL,4,SG) LOADW(bC5,colA+CELL,5,SG)
  LOADW(bD0,colB+CELL,0,SG) LOADW(bD1,colB+CELL,1,SG) LOADW(bD2,colB+CELL,2,SG)
  LOADW(bD3,colB+CELL,3,SG) LOADW(bD4,colB+CELL,4,SG) LOADW(bD5,colB+CELL,5,SG)
#undef LOADW
  // pin weight frags in arch VGPRs (R8-proven; "+a" regressed in R9)
  asm volatile("" : "+v"(bA0),"+v"(bA1),"+v"(bA2),"+v"(bA3),"+v"(bA4),"+v"(bA5),
                    "+v"(bB0),"+v"(bB1),"+v"(bB2),"+v"(bB3),"+v"(bB4),"+v"(bB5),
                    "+v"(bC0),"+v"(bC1),"+v"(bC2),"+v"(bC3),"+v"(bC4),"+v"(bC5),
                    "+v"(bD0),"+v"(bD1),"+v"(bD2),"+v"(bD3),"+v"(bD4),"+v"(bD5));

  const float bA_ = bz[colA] * SF, bB_ = bz[colB] * SF;
  const float bC_ = bz[colA + CELL] * SG, bD_ = bz[colB + CELL] * SG;
  f32x4 bqA = {bA_, bA_, bA_, bA_};
  f32x4 bqB = {bB_, bB_, bB_, bB_};
  f32x4 bqC = {bC_, bC_, bC_, bC_};
  f32x4 bqD = {bD_, bD_, bD_, bD_};
  asm volatile("" : "+v"(bqA), "+v"(bqB), "+v"(bqC), "+v"(bqD));

  // LDS byte offsets
  int ro[4];   // read: row q, cells 32ct+8g..+8
#pragma unroll
  for (int ct = 0; ct < 4; ++ct)
    ro[ct] = q * 256 + 16 * ((4 * ct + g) ^ (q & 7));
  int woPk[4]; // packed write: row 4g+i, cells colA,colB (one u32)
#pragma unroll
  for (int i = 0; i < 4; ++i) {
    const int r = 4 * g + i;
    woPk[i] = r * 256 + 16 * ((4 * w + (q >> 2)) ^ (r & 7)) + ((4 * q) & 15);
  }

  // per-lane x base (row rb+q, k-offset 8g); step offset is uniform
  const float* xbase = in + (size_t)(rb + q) * T * IN + 8 * g;
  // prologue: x(0) -> bufA, x(1) -> bufB
  f4 xc0 = *(const f4*)(xbase);
  f4 xc1 = *(const f4*)(xbase + 4);
  f4 xc2 = *(const f4*)(xbase + 32);
  f4 xc3 = *(const f4*)(xbase + 36);
  f4 xn0 = *(const f4*)(xbase + 64);
  f4 xn1 = *(const f4*)(xbase + 68);
  f4 xn2 = *(const f4*)(xbase + 96);
  f4 xn3 = *(const f4*)(xbase + 100);

  f32x4 cregA = {0.f, 0.f, 0.f, 0.f};   // fp32 master state, col colA
  f32x4 cregB = {0.f, 0.f, 0.f, 0.f};   // fp32 master state, col colB

  __syncthreads();   // c(t=0) zeros visible

  for (int t = 0; t < T; t += 2) {
    STEP(xc0, xc1, xc2, xc3, t, 0)       // even: consumes bufA, refills bufA
    STEP(xn0, xn1, xn2, xn3, t + 1, 1)   // odd:  consumes bufB, refills bufB
  }

  // ---- final c (fp32) to LDS, dense epilogue out = h @ Wd + bd ----
#pragma unroll
  for (int i = 0; i < 4; ++i) {
    cfin[(4 * g + i) * CELL + colA] = cregA[i];
    cfin[(4 * g + i) * CELL + colB] = cregB[i];
  }
  __syncthreads();

  const int o = tid & 63;
  const int rp = tid >> 6;   // 0..3: rows rp, rp+4, rp+8, rp+12
  float a0 = bd[o], a1 = bd[o], a2 = bd[o], a3 = bd[o];
#pragma unroll 4
  for (int k = 0; k < CELL; ++k) {
    const float wv = Wd[(size_t)k * OUTD + o];
    a0 += cfin[rp * CELL + k] * wv;
    a1 += cfin[(rp + 4) * CELL + k] * wv;
    a2 += cfin[(rp + 8) * CELL + k] * wv;
    a3 += cfin[(rp + 12) * CELL + k] * wv;
  }
  out[(size_t)(rb + rp) * OUTD + o] = a0;
  out[(size_t)(rb + rp + 4) * OUTD + o] = a1;
  out[(size_t)(rb + rp + 8) * OUTD + o] = a2;
  out[(size_t)(rb + rp + 12) * OUTD + o] = a3;
}

extern "C" void kernel_launch(void* const* d_in, const int* in_sizes, int n_in,
                              void* d_out, int out_size, void* d_ws, size_t ws_size,
                              hipStream_t stream) {
  const float* in  = (const float*)d_in[0];
  const float* Km  = (const float*)d_in[1];
  const float* Rm  = (const float*)d_in[2];
  const float* bz  = (const float*)d_in[3];
  const float* Wd  = (const float*)d_in[4];
  const float* bd  = (const float*)d_in[5];
  float* out = (float*)d_out;

  dim3 grid(BATCH / M);   // 256 blocks -> 1 per CU
  dim3 block(256);        // 4 waves -> 1 per SIMD
  hipLaunchKernelGGL(llrnn_f16, grid, block, 0, stream,
                     in, Km, Rm, bz, Wd, bd, out);
}

// Round 11
// 149.449 us; speedup vs baseline: 1.3239x; 1.3239x over previous
//
#include <hip/hip_runtime.h>

#define BATCH 4096
#define T 256
#define IN 64
#define CELL 128
#define ZDIM 256
#define OUTD 64
#define M 16   // batch rows per block (one MFMA row-tile)

using f32x4 = __attribute__((ext_vector_type(4))) float;
using f4    = __attribute__((ext_vector_type(4))) float;
using h16x8 = __attribute__((ext_vector_type(8))) _Float16;
using fp16x2 = __attribute__((ext_vector_type(2))) __fp16;   // cvt_pkrtz result type
typedef unsigned int u32t;

union h8cast { h16x8 v; fp16x2 h[4]; };
union pkcast { fp16x2 h; u32t u; };

#define MFMA16(A, B, C) __builtin_amdgcn_mfma_f32_16x16x32_f16(A, B, C, 0, 0, 0)

// gate for cell pair (colA=32w+2q, colB=colA+1) at row 4g+I.
// Weights/biases pre-scaled: f-cols by -log2e, g-cols by 2*log2e, so
// sigmoid(zf) = rcp(1+exp2(zf')) and tanh(zg) = 1-2*rcp(exp2(zg')+1).
#define GATEPK(I)                                                               \
  {                                                                             \
    float fgA = __builtin_amdgcn_rcpf(1.f + __builtin_amdgcn_exp2f(fa[I]));     \
    float thA = 1.f - 2.f * __builtin_amdgcn_rcpf(__builtin_amdgcn_exp2f(ga[I]) + 1.f); \
    float cnA = fgA * (cregA[I] - thA) + thA;                                   \
    float fgB = __builtin_amdgcn_rcpf(1.f + __builtin_amdgcn_exp2f(fb[I]));     \
    float thB = 1.f - 2.f * __builtin_amdgcn_rcpf(__builtin_amdgcn_exp2f(gb[I]) + 1.f); \
    float cnB = fgB * (cregB[I] - thB) + thB;                                   \
    cregA[I] = cnA; cregB[I] = cnB;                                             \
    pkcast pk_; pk_.h = __builtin_amdgcn_cvt_pkrtz(cnA, cnB);                   \
    *(u32t*)(cn_ + woPk[I]) = pk_.u;                                            \
  }

#define CVT8(D0, D1, S0, S1, S2, S3)                                            \
  {                                                                             \
    h8cast u0_, u1_;                                                            \
    u0_.h[0] = __builtin_amdgcn_cvt_pkrtz(S0[0], S0[1]);                        \
    u0_.h[1] = __builtin_amdgcn_cvt_pkrtz(S0[2], S0[3]);                        \
    u0_.h[2] = __builtin_amdgcn_cvt_pkrtz(S1[0], S1[1]);                        \
    u0_.h[3] = __builtin_amdgcn_cvt_pkrtz(S1[2], S1[3]);                        \
    u1_.h[0] = __builtin_amdgcn_cvt_pkrtz(S2[0], S2[1]);                        \
    u1_.h[1] = __builtin_amdgcn_cvt_pkrtz(S2[2], S2[3]);                        \
    u1_.h[2] = __builtin_amdgcn_cvt_pkrtz(S3[0], S3[1]);                        \
    u1_.h[3] = __builtin_amdgcn_cvt_pkrtz(S3[2], S3[3]);                        \
    D0 = u0_.v; D1 = u1_.v;                                                     \
  }

// One recurrence step at time TT (parity CUR), P = LDS read buffer.
// Phase b: zx(TT+1) from xa_NXT (x(TT+1)) -> zx*NXT quads (next step's seed).
// Phase c: c-chains depth 4, seeded zx*CUR (= bias + x(TT)@K, from last step).
// Phase d: convert xr_CUR (x(TT+2)) -> xa_CUR; refill xr_CUR <- x(TT+4).
#define STEP(CUR, NXT, TT, P)                                                   \
  {                                                                             \
    const char* cb_ = cbuf[P];                                                  \
    h16x8 ca0 = *(const h16x8*)(cb_ + ro[0]);                                   \
    h16x8 ca1 = *(const h16x8*)(cb_ + ro[1]);                                   \
    h16x8 ca2 = *(const h16x8*)(cb_ + ro[2]);                                   \
    h16x8 ca3 = *(const h16x8*)(cb_ + ro[3]);                                   \
    /* zx for TT+1: independent MFMAs issue during ds_read latency */           \
    zxf##NXT##A = MFMA16(xa_##NXT##0, bA0, bqA);                                \
    zxf##NXT##B = MFMA16(xa_##NXT##0, bB0, bqB);                                \
    zxg##NXT##A = MFMA16(xa_##NXT##0, bC0, bqC);                                \
    zxg##NXT##B = MFMA16(xa_##NXT##0, bD0, bqD);                                \
    zxf##NXT##A = MFMA16(xa_##NXT##1, bA1, zxf##NXT##A);                        \
    zxf##NXT##B = MFMA16(xa_##NXT##1, bB1, zxf##NXT##B);                        \
    zxg##NXT##A = MFMA16(xa_##NXT##1, bC1, zxg##NXT##A);                        \
    zxg##NXT##B = MFMA16(xa_##NXT##1, bD1, zxg##NXT##B);                        \
    /* c-chains: 4 parallel, depth 4, seeded with zx(TT) */                     \
    f32x4 fa = MFMA16(ca0, bA2, zxf##CUR##A);                                   \
    f32x4 fb = MFMA16(ca0, bB2, zxf##CUR##B);                                   \
    f32x4 ga = MFMA16(ca0, bC2, zxg##CUR##A);                                   \
    f32x4 gb = MFMA16(ca0, bD2, zxg##CUR##B);                                   \
    fa = MFMA16(ca1, bA3, fa); fb = MFMA16(ca1, bB3, fb);                       \
    ga = MFMA16(ca1, bC3, ga); gb = MFMA16(ca1, bD3, gb);                       \
    fa = MFMA16(ca2, bA4, fa); fb = MFMA16(ca2, bB4, fb);                       \
    ga = MFMA16(ca2, bC4, ga); gb = MFMA16(ca2, bD4, gb);                       \
    fa = MFMA16(ca3, bA5, fa); fb = MFMA16(ca3, bB5, fb);                       \
    ga = MFMA16(ca3, bC5, ga); gb = MFMA16(ca3, bD5, gb);                       \
    /* convert x(TT+2) for the next zx; refill raw regs with x(TT+4) */         \
    CVT8(xa_##CUR##0, xa_##CUR##1, xr_##CUR##0, xr_##CUR##1, xr_##CUR##2, xr_##CUR##3) \
    {                                                                           \
      const int tn = ((TT) + 4) & (T - 1);                                      \
      const float* xp = xbase + (size_t)tn * IN;                                \
      xr_##CUR##0 = *(const f4*)(xp);                                           \
      xr_##CUR##1 = *(const f4*)(xp + 4);                                       \
      xr_##CUR##2 = *(const f4*)(xp + 32);                                      \
      xr_##CUR##3 = *(const f4*)(xp + 36);                                      \
    }                                                                           \
    char* cn_ = cbuf[(P) ^ 1];                                                  \
    GATEPK(0) GATEPK(1) GATEPK(2) GATEPK(3)                                     \
    /* LDS-only barrier: ds_writes visible, global prefetch stays in flight */  \
    asm volatile("s_waitcnt lgkmcnt(0)\n\ts_barrier" ::: "memory");             \
  }

__global__ __launch_bounds__(256, 1)
void llrnn_f16(const float* __restrict__ in,   // [B,T,IN]
               const float* __restrict__ Km,   // [IN,ZDIM]
               const float* __restrict__ Rm,   // [CELL,ZDIM]
               const float* __restrict__ bz,   // [ZDIM]
               const float* __restrict__ Wd,   // [CELL,OUTD]
               const float* __restrict__ bd,   // [OUTD]
               float* __restrict__ out)        // [B,OUTD]
{
  // c state as fp16 [16 rows][128 cells], chunk-XOR-swizzled, double-buffered.
  // byte(r,j) = r*256 + 16*((j>>3)^(r&7)) + (2j&15)
  __shared__ __align__(16) char cbuf[2][M * CELL * 2];   // 2 x 4 KB
  __shared__ float cfin[M * CELL];

  const int tid = threadIdx.x;
  const int w = tid >> 6;        // wave 0..3
  const int l = tid & 63;
  const int q = l & 15;          // A-row / D-col within tile
  const int g = l >> 4;          // k-group 0..3
  const int rb = blockIdx.x * M;
  const int colA = 32 * w + 2 * q;    // even cell column owned by this lane
  const int colB = colA + 1;          // odd cell column (adjacent -> packed write)

  // zero c(t=0) buffer (4 KB, 256 threads x 4 u32)
  {
    u32t* z0 = (u32t*)cbuf[0];
    z0[tid] = 0; z0[tid + 256] = 0; z0[tid + 512] = 0; z0[tid + 768] = 0;
  }

  const float SF = -1.44269504f;  // -log2(e): fold into f-gate weights
  const float SG =  2.88539008f;  //  2*log2(e): fold into g-gate weights

  // ---- preload scaled weight columns as fp16 frags (A=f even, B=f odd,
  //      C=g even, D=g odd), pinned in arch VGPRs ----
  h16x8 bA0,bA1,bA2,bA3,bA4,bA5, bB0,bB1,bB2,bB3,bB4,bB5,
        bC0,bC1,bC2,bC3,bC4,bC5, bD0,bD1,bD2,bD3,bD4,bD5;
#define LOADW(DST, COL, KT, SC)                                                 \
  {                                                                             \
    _Pragma("unroll") for (int e = 0; e < 8; ++e) {                             \
      const int krow = 32 * (KT) + 8 * g + e;                                   \
      const float* src = ((KT) < 2) ? (Km + (size_t)krow * ZDIM)                \
                                    : (Rm + (size_t)(krow - IN) * ZDIM);        \
      DST[e] = (_Float16)(src[COL] * (SC));                                     \
    }                                                                           \
  }
  LOADW(bA0,colA,0,SF) LOADW(bA1,colA,1,SF) LOADW(bA2,colA,2,SF)
  LOADW(bA3,colA,3,SF) LOADW(bA4,colA,4,SF) LOADW(bA5,colA,5,SF)
  LOADW(bB0,colB,0,SF) LOADW(bB1,colB,1,SF) LOADW(bB2,colB,2,SF)
  LOADW(bB3,colB,3,SF) LOADW(bB4,colB,4,SF) LOADW(bB5,colB,5,SF)
  LOADW(bC0,colA+CELL,0,SG) LOADW(bC1,colA+CELL,1,SG) LOADW(bC2,colA+CELL,2,SG)
  LOADW(bC3,colA+CELL,3,SG) LOADW(bC4,colA+CELL,4,SG) LOADW(bC5,colA+CELL,5,SG)
  LOADW(bD0,colB+CELL,0,SG) LOADW(bD1,colB+CELL,1,SG) LOADW(bD2,colB+CELL,2,SG)
  LOADW(bD3,colB+CELL,3,SG) LOADW(bD4,colB+CELL,4,SG) LOADW(bD5,colB+CELL,5,SG)
#undef LOADW
  // pin weight frags in arch VGPRs (R8-proven; "+a" regressed in R9)
  asm volatile("" : "+v"(bA0),"+v"(bA1),"+v"(bA2),"+v"(bA3),"+v"(bA4),"+v"(bA5),
                    "+v"(bB0),"+v"(bB1),"+v"(bB2),"+v"(bB3),"+v"(bB4),"+v"(bB5),
                    "+v"(bC0),"+v"(bC1),"+v"(bC2),"+v"(bC3),"+v"(bC4),"+v"(bC5),
                    "+v"(bD0),"+v"(bD1),"+v"(bD2),"+v"(bD3),"+v"(bD4),"+v"(bD5));

  const float bA_ = bz[colA] * SF, bB_ = bz[colB] * SF;
  const float bC_ = bz[colA + CELL] * SG, bD_ = bz[colB + CELL] * SG;
  f32x4 bqA = {bA_, bA_, bA_, bA_};
  f32x4 bqB = {bB_, bB_, bB_, bB_};
  f32x4 bqC = {bC_, bC_, bC_, bC_};
  f32x4 bqD = {bD_, bD_, bD_, bD_};
  asm volatile("" : "+v"(bqA), "+v"(bqB), "+v"(bqC), "+v"(bqD));

  // LDS byte offsets
  int ro[4];   // read: row q, cells 32ct+8g..+8
#pragma unroll
  for (int ct = 0; ct < 4; ++ct)
    ro[ct] = q * 256 + 16 * ((4 * ct + g) ^ (q & 7));
  int woPk[4]; // packed write: row 4g+i, cells colA,colB (one u32)
#pragma unroll
  for (int i = 0; i < 4; ++i) {
    const int r = 4 * g + i;
    woPk[i] = r * 256 + 16 * ((4 * w + (q >> 2)) ^ (r & 7)) + ((4 * q) & 15);
  }

  // per-lane x base (row rb+q, k-offset 8g); step offset is uniform
  const float* xbase = in + (size_t)(rb + q) * T * IN + 8 * g;

  // ---- prologue: x(0),x(1) loaded+converted; zx(0) computed; xr <- x(2),x(3)
  f4 xr_E0 = *(const f4*)(xbase);
  f4 xr_E1 = *(const f4*)(xbase + 4);
  f4 xr_E2 = *(const f4*)(xbase + 32);
  f4 xr_E3 = *(const f4*)(xbase + 36);
  f4 xr_O0 = *(const f4*)(xbase + IN);
  f4 xr_O1 = *(const f4*)(xbase + IN + 4);
  f4 xr_O2 = *(const f4*)(xbase + IN + 32);
  f4 xr_O3 = *(const f4*)(xbase + IN + 36);

  h16x8 xa_E0, xa_E1, xa_O0, xa_O1;
  CVT8(xa_E0, xa_E1, xr_E0, xr_E1, xr_E2, xr_E3)   // x(0)
  CVT8(xa_O0, xa_O1, xr_O0, xr_O1, xr_O2, xr_O3)   // x(1)

  f32x4 zxfEA, zxfEB, zxgEA, zxgEB, zxfOA, zxfOB, zxgOA, zxgOB;
  // zx(0) = bias + x(0)@K
  zxfEA = MFMA16(xa_E0, bA0, bqA);
  zxfEB = MFMA16(xa_E0, bB0, bqB);
  zxgEA = MFMA16(xa_E0, bC0, bqC);
  zxgEB = MFMA16(xa_E0, bD0, bqD);
  zxfEA = MFMA16(xa_E1, bA1, zxfEA);
  zxfEB = MFMA16(xa_E1, bB1, zxfEB);
  zxgEA = MFMA16(xa_E1, bC1, zxgEA);
  zxgEB = MFMA16(xa_E1, bD1, zxgEB);

  // refill raw regs: xr_E <- x(2), xr_O <- x(3)
  xr_E0 = *(const f4*)(xbase + 2 * IN);
  xr_E1 = *(const f4*)(xbase + 2 * IN + 4);
  xr_E2 = *(const f4*)(xbase + 2 * IN + 32);
  xr_E3 = *(const f4*)(xbase + 2 * IN + 36);
  xr_O0 = *(const f4*)(xbase + 3 * IN);
  xr_O1 = *(const f4*)(xbase + 3 * IN + 4);
  xr_O2 = *(const f4*)(xbase + 3 * IN + 32);
  xr_O3 = *(const f4*)(xbase + 3 * IN + 36);

  f32x4 cregA = {0.f, 0.f, 0.f, 0.f};   // fp32 master state, col colA
  f32x4 cregB = {0.f, 0.f, 0.f, 0.f};   // fp32 master state, col colB

  __syncthreads();   // c(t=0) zeros visible

  for (int t = 0; t < T; t += 2) {
    STEP(E, O, t, 0)       // even: consumes zxE, produces zxO; cbuf[0]->[1]
    STEP(O, E, t + 1, 1)   // odd:  consumes zxO, produces zxE; cbuf[1]->[0]
  }

  // ---- final c (fp32) to LDS, dense epilogue out = h @ Wd + bd ----
#pragma unroll
  for (int i = 0; i < 4; ++i) {
    cfin[(4 * g + i) * CELL + colA] = cregA[i];
    cfin[(4 * g + i) * CELL + colB] = cregB[i];
  }
  __syncthreads();

  const int o = tid & 63;
  const int rp = tid >> 6;   // 0..3: rows rp, rp+4, rp+8, rp+12
  float a0 = bd[o], a1 = bd[o], a2 = bd[o], a3 = bd[o];
#pragma unroll 4
  for (int k = 0; k < CELL; ++k) {
    const float wv = Wd[(size_t)k * OUTD + o];
    a0 += cfin[rp * CELL + k] * wv;
    a1 += cfin[(rp + 4) * CELL + k] * wv;
    a2 += cfin[(rp + 8) * CELL + k] * wv;
    a3 += cfin[(rp + 12) * CELL + k] * wv;
  }
  out[(size_t)(rb + rp) * OUTD + o] = a0;
  out[(size_t)(rb + rp + 4) * OUTD + o] = a1;
  out[(size_t)(rb + rp + 8) * OUTD + o] = a2;
  out[(size_t)(rb + rp + 12) * OUTD + o] = a3;
}

extern "C" void kernel_launch(void* const* d_in, const int* in_sizes, int n_in,
                              void* d_out, int out_size, void* d_ws, size_t ws_size,
                              hipStream_t stream) {
  const float* in  = (const float*)d_in[0];
  const float* Km  = (const float*)d_in[1];
  const float* Rm  = (const float*)d_in[2];
  const float* bz  = (const float*)d_in[3];
  const float* Wd  = (const float*)d_in[4];
  const float* bd  = (const float*)d_in[5];
  float* out = (float*)d_out;

  dim3 grid(BATCH / M);   // 256 blocks -> 1 per CU
  dim3 block(256);        // 4 waves -> 1 per SIMD
  hipLaunchKernelGGL(llrnn_f16, grid, block, 0, stream,
                     in, Km, Rm, bz, Wd, bd, out);
}